// Round 6
// baseline (162.195 us; speedup 1.0000x reference)
//
#include <hip/hip_runtime.h>

#define N      4096
#define NIN    64
#define NHID   32
#define NOUT   64
#define NHEADS 8
#define H_SP   6
#define D_INT  32
#define MAXDEG 128
#define WCAP   80     // per-wave (1024-col segment) neighbor cap; ~21 sigma out
#define ALPHA  0.2f

typedef float vf4 __attribute__((ext_vector_type(4)));   // native vec for nontemporal builtins

// ---------------------------------------------------------------------------
// K1 (fused proj + csr): one block per node n.
//  - adj row loads issued first (nontemporal: single-use 67 MB stream, keep
//    L2 for Wh_t/col which K2 re-reads) so HBM latency hides behind proj FMAs.
//  - 8 head-groups x 32 lanes compute Wh row (node-major [n][256]) and the
//    rank-1 score halves src[h][n], dst_t[n][h].
//  - 4 waves x 4 vec4-iters compact the adjacency row into col/deg.
// ---------------------------------------------------------------------------
__global__ __launch_bounds__(256) void k_fused1(
    const float* __restrict__ x, const float* __restrict__ ie,
    const vf4* __restrict__ adj4,
    const float* __restrict__ Wsp, const float* __restrict__ asp,
    const float* __restrict__ Wint, const float* __restrict__ aint,
    float* __restrict__ Wh_t, float* __restrict__ src, float* __restrict__ dst_t,
    int* __restrict__ col, int* __restrict__ deg)
{
    const int n    = blockIdx.x;
    const int tid  = threadIdx.x;
    const int wv   = tid >> 6, lane = tid & 63;
    const int h    = tid >> 5, f    = tid & 31;

    __shared__ float xs[NIN];
    __shared__ float ies[D_INT];
    __shared__ int   wbuf[4][WCAP];
    __shared__ int   wcnt[4];

    // --- adj prefetch: 4 vec4/lane, nontemporal, issued before compute ---
    const vf4* row = adj4 + (size_t)n * (N / 4) + wv * 256 + lane;
    vf4 a0 = __builtin_nontemporal_load(row);
    vf4 a1 = __builtin_nontemporal_load(row + 64);
    vf4 a2 = __builtin_nontemporal_load(row + 128);
    vf4 a3 = __builtin_nontemporal_load(row + 192);

    if (tid < NIN) xs[tid] = x[n * NIN + tid];
    else if (tid < NIN + D_INT) ies[tid - NIN] = ie[n * D_INT + (tid - NIN)];
    __syncthreads();

    // --- projection (8 heads x 32 feats), 2-acc ILP ---
    const float* W = (h < H_SP) ? (Wsp + h * NIN * NHID)
                                : (Wint + (h - H_SP) * NIN * NHID);
    float acc0 = 0.f, acc1 = 0.f;
#pragma unroll
    for (int c = 0; c < NIN; c += 2) {
        acc0 += xs[c]     * W[c * NHID + f];
        acc1 += xs[c + 1] * W[(c + 1) * NHID + f];
    }
    const float acc = acc0 + acc1;
    Wh_t[(size_t)n * 256 + tid] = acc;          // node-major: tid == h*32+f

    float s1, s2;
    if (h < H_SP) {
        s1 = acc * asp[h * 2 * NHID + f];
        s2 = acc * asp[h * 2 * NHID + NHID + f];
    } else {
        float v = ies[f];
        s1 = v * aint[(h - H_SP) * 2 * D_INT + f];
        s2 = v * aint[(h - H_SP) * 2 * D_INT + D_INT + f];
    }
#pragma unroll
    for (int m = 16; m >= 1; m >>= 1) {
        s1 += __shfl_xor(s1, m);
        s2 += __shfl_xor(s2, m);
    }
    if (f == 0) { src[h * N + n] = s1; dst_t[n * 8 + h] = s2; }

    // --- csr compaction: each wave handles 1024 cols (4 iters of 64 lanes) ---
    int cnt = 0;
#pragma unroll
    for (int t = 0; t < 4; ++t) {
        vf4 v = (t == 0) ? a0 : (t == 1) ? a1 : (t == 2) ? a2 : a3;
        unsigned nib = (v.x > 0.f ? 1u : 0u) | (v.y > 0.f ? 2u : 0u)
                     | (v.z > 0.f ? 4u : 0u) | (v.w > 0.f ? 8u : 0u);
        int c = __popc(nib);
        int scan = c;
#pragma unroll
        for (int m = 1; m <= 32; m <<= 1) {
            int o = __shfl_up(scan, m);
            if (lane >= m) scan += o;
        }
        int pos = cnt + scan - c;            // exclusive prefix within wave seg
        int idx0 = (wv * 256 + t * 64 + lane) * 4;
        if (nib) {
            if (nib & 1u) { if (pos < WCAP) wbuf[wv][pos] = idx0;     ++pos; }
            if (nib & 2u) { if (pos < WCAP) wbuf[wv][pos] = idx0 + 1; ++pos; }
            if (nib & 4u) { if (pos < WCAP) wbuf[wv][pos] = idx0 + 2; ++pos; }
            if (nib & 8u) { if (pos < WCAP) wbuf[wv][pos] = idx0 + 3; ++pos; }
        }
        cnt += __shfl(scan, 63);
    }
    if (lane == 0) wcnt[wv] = cnt;
    __syncthreads();

    const int c0 = wcnt[0], c1 = wcnt[1], c2 = wcnt[2], c3 = wcnt[3];
    const int off = (wv > 0 ? c0 : 0) + (wv > 1 ? c1 : 0) + (wv > 2 ? c2 : 0);
    const int my = (wcnt[wv] < WCAP) ? wcnt[wv] : WCAP;
    for (int i = lane; i < my; i += 64) {
        int p = off + i;
        if (p < MAXDEG) col[n * MAXDEG + p] = wbuf[wv][i];
    }
    if (tid == 0) {
        int tot = c0 + c1 + c2 + c3;
        deg[n] = (tot < MAXDEG) ? tot : MAXDEG;
    }
}

// ---------------------------------------------------------------------------
// K2 (fused attn1 + Who): one block per destination node.
//  - per-head sparse softmax; weights (0-padded to 128) in LDS.
//  - aggregation: 8 neighbors/iteration -> 8 independent coalesced row loads
//    in flight per thread, 2 accumulators. Padded slots hit node 0 with w=0.
//  - elu -> concat row in LDS -> Who GEMV + o1/o2 dots.
// ---------------------------------------------------------------------------
__global__ __launch_bounds__(256) void k_attn1who(
    const int* __restrict__ col, const int* __restrict__ deg,
    const float* __restrict__ Wh_t, const float* __restrict__ src,
    const float* __restrict__ dst_t, const float* __restrict__ Wout,
    const float* __restrict__ aout,
    float* __restrict__ Who, float* __restrict__ o1, float* __restrict__ o2)
{
    const int r   = blockIdx.x;
    const int tid = threadIdx.x;
    const int h   = tid >> 5, lane = tid & 31;

    __shared__ int   cs[MAXDEG];
    __shared__ float w[NHEADS][MAXDEG];
    __shared__ float hs[NHEADS * NHID];
    __shared__ float part[4][NOUT];

    const int d  = deg[r];
    const int d8 = (d + 7) & ~7;
    for (int k = tid; k < MAXDEG; k += 256)
        cs[k] = (k < d) ? col[r * MAXDEG + k] : 0;   // pad with node 0 (w=0)
    __syncthreads();

    // --- per-head sparse softmax ---
    const float sr = src[h * N + r];
    float ev[4];
    float mx = -3.4e38f;
#pragma unroll
    for (int t = 0; t < 4; ++t) {
        int k = lane + t * 32;
        float e = -3.4e38f;
        if (k < d) {
            e = sr + dst_t[cs[k] * 8 + h];
            e = e > 0.f ? e : ALPHA * e;
        }
        ev[t] = e;
        mx = fmaxf(mx, e);
    }
#pragma unroll
    for (int m = 16; m >= 1; m >>= 1) mx = fmaxf(mx, __shfl_xor(mx, m));

    float sum = 0.f;
#pragma unroll
    for (int t = 0; t < 4; ++t) {
        int k = lane + t * 32;
        float p = (k < d) ? __expf(ev[t] - mx) : 0.f;
        ev[t] = p;
        sum += p;
    }
#pragma unroll
    for (int m = 16; m >= 1; m >>= 1) sum += __shfl_xor(sum, m);
    const float inv = 1.f / sum;

#pragma unroll
    for (int t = 0; t < 4; ++t) {               // write ALL 128 slots (0 pad)
        int k = lane + t * 32;
        w[h][k] = (k < d) ? ev[t] * inv : 0.f;
    }
    __syncthreads();

    // --- aggregation: 8-wide, branch-free, 2 accumulators ---
    float acc0 = 0.f, acc1 = 0.f;
    for (int k = 0; k < d8; k += 8) {
        int4   ja = *(const int4*)  &cs[k];
        int4   jb = *(const int4*)  &cs[k + 4];
        float4 wa = *(const float4*)&w[h][k];
        float4 wb = *(const float4*)&w[h][k + 4];
        float g0 = Wh_t[(size_t)ja.x * 256 + tid];
        float g1 = Wh_t[(size_t)ja.y * 256 + tid];
        float g2 = Wh_t[(size_t)ja.z * 256 + tid];
        float g3 = Wh_t[(size_t)ja.w * 256 + tid];
        float g4 = Wh_t[(size_t)jb.x * 256 + tid];
        float g5 = Wh_t[(size_t)jb.y * 256 + tid];
        float g6 = Wh_t[(size_t)jb.z * 256 + tid];
        float g7 = Wh_t[(size_t)jb.w * 256 + tid];
        acc0 += wa.x * g0 + wa.y * g1 + wa.z * g2 + wa.w * g3;
        acc1 += wb.x * g4 + wb.y * g5 + wb.z * g6 + wb.w * g7;
    }
    float acc = acc0 + acc1;
    acc = acc > 0.f ? acc : __expf(acc) - 1.f;   // elu (concat heads)
    hs[tid] = acc;
    __syncthreads();

    // --- Who[r,:] = hrow @ W_out, split over 4 waves ---
    const int fo = tid & 63, q = tid >> 6;
    float p = 0.f;
#pragma unroll
    for (int c = q * 64; c < q * 64 + 64; ++c) p += hs[c] * Wout[c * NOUT + fo];
    part[q][fo] = p;
    __syncthreads();

    if (tid < 64) {
        float who = part[0][tid] + part[1][tid] + part[2][tid] + part[3][tid];
        Who[(size_t)r * NOUT + tid] = who;
        float v1 = who * aout[tid];
        float v2 = who * aout[NOUT + tid];
#pragma unroll
        for (int m = 32; m >= 1; m >>= 1) {
            v1 += __shfl_xor(v1, m);
            v2 += __shfl_xor(v2, m);
        }
        if (tid == 0) { o1[r] = v1; o2[r] = v2; }
    }
}

// ---------------------------------------------------------------------------
// K3 (attn2): one block (256 thr) per row. Block softmax over neighbors;
// gather split-k across 4 waves in 8-wide groups (8 loads in flight), LDS
// combine; tanh; fp32 store.
// ---------------------------------------------------------------------------
__global__ __launch_bounds__(256) void k_attn2(
    const int* __restrict__ col, const int* __restrict__ deg,
    const float* __restrict__ Who, const float* __restrict__ o1,
    const float* __restrict__ o2, float* __restrict__ out)
{
    const int r   = blockIdx.x;
    const int tid = threadIdx.x;
    const int wv  = tid >> 6, lane = tid & 63;

    __shared__ int   cs[MAXDEG];
    __shared__ float w[MAXDEG];
    __shared__ float part[4][NOUT];
    __shared__ float redm[4], reds[4];

    const int d = deg[r];
    for (int k = tid; k < MAXDEG; k += 256)
        cs[k] = (k < d) ? col[r * MAXDEG + k] : 0;
    __syncthreads();

    // --- scores (tid<128 holds one neighbor each) + block softmax ---
    const float sr = o1[r];
    float e = -3.4e38f;
    if (tid < d) {
        e = sr + o2[cs[tid]];
        e = e > 0.f ? e : ALPHA * e;
    }
    float mx = e;
#pragma unroll
    for (int m = 32; m >= 1; m >>= 1) mx = fmaxf(mx, __shfl_xor(mx, m));
    if (lane == 0) redm[wv] = mx;
    __syncthreads();
    mx = fmaxf(fmaxf(redm[0], redm[1]), fmaxf(redm[2], redm[3]));

    float p = (tid < d) ? __expf(e - mx) : 0.f;
    float s = p;
#pragma unroll
    for (int m = 32; m >= 1; m >>= 1) s += __shfl_xor(s, m);
    if (lane == 0) reds[wv] = s;
    __syncthreads();
    const float inv = 1.f / (reds[0] + reds[1] + reds[2] + reds[3]);
    if (tid < MAXDEG) w[tid] = p * inv;          // zeros beyond d
    __syncthreads();

    // --- gather split-k: wave wv takes 8-wide groups {wv*8, wv*8+32, ...} ---
    const int kup = (d + 31) & ~31;              // padded: w=0, cs=0 beyond d
    float acc0 = 0.f, acc1 = 0.f;
    for (int k = wv * 8; k < kup; k += 32) {
        int4   ja = *(const int4*)  &cs[k];
        int4   jb = *(const int4*)  &cs[k + 4];
        float4 wa = *(const float4*)&w[k];
        float4 wb = *(const float4*)&w[k + 4];
        acc0 += wa.x * Who[(size_t)ja.x * NOUT + lane];
        acc0 += wa.y * Who[(size_t)ja.y * NOUT + lane];
        acc0 += wa.z * Who[(size_t)ja.z * NOUT + lane];
        acc0 += wa.w * Who[(size_t)ja.w * NOUT + lane];
        acc1 += wb.x * Who[(size_t)jb.x * NOUT + lane];
        acc1 += wb.y * Who[(size_t)jb.y * NOUT + lane];
        acc1 += wb.z * Who[(size_t)jb.z * NOUT + lane];
        acc1 += wb.w * Who[(size_t)jb.w * NOUT + lane];
    }
    part[wv][lane] = acc0 + acc1;
    __syncthreads();

    if (tid < NOUT)
        out[(size_t)r * NOUT + tid] =
            tanhf(part[0][tid] + part[1][tid] + part[2][tid] + part[3][tid]);
}

// ---------------------------------------------------------------------------
extern "C" void kernel_launch(void* const* d_in, const int* in_sizes, int n_in,
                              void* d_out, int out_size, void* d_ws, size_t ws_size,
                              hipStream_t stream) {
    const float* x    = (const float*)d_in[0];   // [4096,64]
    const float* adj  = (const float*)d_in[1];   // [4096,4096]
    const float* ie   = (const float*)d_in[2];   // [4096,32]
    const float* Wsp  = (const float*)d_in[3];   // [6,64,32]
    const float* asp  = (const float*)d_in[4];   // [6,64]
    const float* Wint = (const float*)d_in[5];   // [2,64,32]
    const float* aint = (const float*)d_in[6];   // [2,64]
    const float* Wout = (const float*)d_in[7];   // [256,64]
    const float* aout = (const float*)d_in[8];   // [128]
    float* out = (float*)d_out;                  // [4096,64]

    float* ws    = (float*)d_ws;
    float* Wh_t  = ws;                    // [4096][256]  node-major
    float* src   = Wh_t + 1048576;        // [8][4096]
    float* dst_t = src  + 32768;          // [4096][8]
    float* Who   = dst_t + 32768;         // [4096][64]
    float* o1    = Who  + 262144;         // [4096]
    float* o2    = o1   + 4096;           // [4096]
    int*   col   = (int*)(o2 + 4096);     // [4096][128]
    int*   deg   = col + 4096 * MAXDEG;   // [4096]

    k_fused1  <<<N, 256, 0, stream>>>(x, ie, (const vf4*)adj, Wsp, asp,
                                      Wint, aint, Wh_t, src, dst_t, col, deg);
    k_attn1who<<<N, 256, 0, stream>>>(col, deg, Wh_t, src, dst_t, Wout, aout,
                                      Who, o1, o2);
    k_attn2   <<<N, 256, 0, stream>>>(col, deg, Who, o1, o2, out);
}

// Round 7
// 156.663 us; speedup vs baseline: 1.0353x; 1.0353x over previous
//
#include <hip/hip_runtime.h>

#define N      4096
#define NIN    64
#define NHID   32
#define NOUT   64
#define NHEADS 8
#define H_SP   6
#define D_INT  32
#define MAXDEG 128
#define NPB    4      // nodes per block in K1 (W-traffic amortization)
#define ALPHA  0.2f

// ---------------------------------------------------------------------------
// K1 (fused proj + csr), 4 nodes per block, 1024 blocks:
//  - projection inverted: one W element load feeds 4 FMAs (amortizes the
//    64 KB/block weight re-read: 268 MB -> 67 MB of L2 traffic).
//  - scores: 2*NHID == 2*D_INT == 64, so spatial/intent share indexing.
//  - csr: each wave compacts ONE full adj row (16 float4 iters, unroll 4 so
//    loads hoist above the scan chain); no cross-wave merge.
// ---------------------------------------------------------------------------
__global__ __launch_bounds__(256) void k_fused1(
    const float* __restrict__ x, const float* __restrict__ ie,
    const float4* __restrict__ adj4,
    const float* __restrict__ Wsp, const float* __restrict__ asp,
    const float* __restrict__ Wint, const float* __restrict__ aint,
    float* __restrict__ Wh_t, float* __restrict__ src, float* __restrict__ dst_t,
    int* __restrict__ col, int* __restrict__ deg)
{
    const int nb   = blockIdx.x * NPB;
    const int tid  = threadIdx.x;
    const int wv   = tid >> 6, lane = tid & 63;
    const int h    = tid >> 5, f    = tid & 31;

    __shared__ float xs[NPB][NIN];
    __shared__ float ies[NPB][D_INT];

    // contiguous block loads: 4 nodes' x rows = 1024 floats, ie rows = 128
    xs[tid >> 6][tid & 63] = x[nb * NIN + tid];
    if (tid < NPB * D_INT) ies[tid >> 5][tid & 31] = ie[nb * D_INT + tid];
    __syncthreads();

    // --- projection: 8 head-groups x 32 lanes, 4 nodes each ---
    const float* W = (h < H_SP) ? (Wsp + h * NIN * NHID)
                                : (Wint + (h - H_SP) * NIN * NHID);
    float acc[NPB] = {0.f, 0.f, 0.f, 0.f};
#pragma unroll
    for (int c = 0; c < NIN; ++c) {
        const float wval = W[c * NHID + f];
#pragma unroll
        for (int m = 0; m < NPB; ++m) acc[m] += xs[m][c] * wval;
    }
#pragma unroll
    for (int m = 0; m < NPB; ++m)
        Wh_t[(size_t)(nb + m) * 256 + tid] = acc[m];   // coalesced 1 KB stores

    // --- rank-1 score halves (2*NHID == 2*D_INT == 64) ---
    const float a1v = (h < H_SP) ? asp[h * 64 + f]      : aint[(h - H_SP) * 64 + f];
    const float a2v = (h < H_SP) ? asp[h * 64 + 32 + f] : aint[(h - H_SP) * 64 + 32 + f];
#pragma unroll
    for (int m = 0; m < NPB; ++m) {
        const float b = (h < H_SP) ? acc[m] : ies[m][f];
        float s1 = b * a1v, s2 = b * a2v;
#pragma unroll
        for (int mm = 16; mm >= 1; mm >>= 1) {
            s1 += __shfl_xor(s1, mm);
            s2 += __shfl_xor(s2, mm);
        }
        if (f == 0) { src[h * N + nb + m] = s1; dst_t[(nb + m) * 8 + h] = s2; }
    }

    // --- csr: wave wv compacts row nb+wv (whole row, ascending order) ---
    const int r = nb + wv;
    const float4* row = adj4 + (size_t)r * (N / 4);
    int cnt = 0;
#pragma unroll 4
    for (int t = 0; t < 16; ++t) {
        float4 v = row[t * 64 + lane];
        unsigned nib = (v.x > 0.f ? 1u : 0u) | (v.y > 0.f ? 2u : 0u)
                     | (v.z > 0.f ? 4u : 0u) | (v.w > 0.f ? 8u : 0u);
        int c = __popc(nib);
        int scan = c;
#pragma unroll
        for (int m = 1; m <= 32; m <<= 1) {
            int o = __shfl_up(scan, m);
            if (lane >= m) scan += o;
        }
        int pos = cnt + scan - c;            // exclusive prefix
        int idx0 = (t * 64 + lane) * 4;
        if (nib) {
            if (nib & 1u) { if (pos < MAXDEG) col[r * MAXDEG + pos] = idx0;     ++pos; }
            if (nib & 2u) { if (pos < MAXDEG) col[r * MAXDEG + pos] = idx0 + 1; ++pos; }
            if (nib & 4u) { if (pos < MAXDEG) col[r * MAXDEG + pos] = idx0 + 2; ++pos; }
            if (nib & 8u) { if (pos < MAXDEG) col[r * MAXDEG + pos] = idx0 + 3; ++pos; }
        }
        cnt += __shfl(scan, 63);
    }
    if (lane == 0) deg[r] = (cnt < MAXDEG) ? cnt : MAXDEG;
}

// ---------------------------------------------------------------------------
// K2 (fused attn1 + Who): one block per destination node.
// ---------------------------------------------------------------------------
__global__ __launch_bounds__(256) void k_attn1who(
    const int* __restrict__ col, const int* __restrict__ deg,
    const float* __restrict__ Wh_t, const float* __restrict__ src,
    const float* __restrict__ dst_t, const float* __restrict__ Wout,
    const float* __restrict__ aout,
    float* __restrict__ Who, float* __restrict__ o1, float* __restrict__ o2)
{
    const int r   = blockIdx.x;
    const int tid = threadIdx.x;
    const int h   = tid >> 5, lane = tid & 31;

    __shared__ int   cs[MAXDEG];
    __shared__ float w[NHEADS][MAXDEG];
    __shared__ float hs[NHEADS * NHID];
    __shared__ float part[4][NOUT];

    const int d  = deg[r];
    const int d8 = (d + 7) & ~7;
    for (int k = tid; k < MAXDEG; k += 256)
        cs[k] = (k < d) ? col[r * MAXDEG + k] : 0;   // pad with node 0 (w=0)
    __syncthreads();

    // --- per-head sparse softmax ---
    const float sr = src[h * N + r];
    float ev[4];
    float mx = -3.4e38f;
#pragma unroll
    for (int t = 0; t < 4; ++t) {
        int k = lane + t * 32;
        float e = -3.4e38f;
        if (k < d) {
            e = sr + dst_t[cs[k] * 8 + h];
            e = e > 0.f ? e : ALPHA * e;
        }
        ev[t] = e;
        mx = fmaxf(mx, e);
    }
#pragma unroll
    for (int m = 16; m >= 1; m >>= 1) mx = fmaxf(mx, __shfl_xor(mx, m));

    float sum = 0.f;
#pragma unroll
    for (int t = 0; t < 4; ++t) {
        int k = lane + t * 32;
        float p = (k < d) ? __expf(ev[t] - mx) : 0.f;
        ev[t] = p;
        sum += p;
    }
#pragma unroll
    for (int m = 16; m >= 1; m >>= 1) sum += __shfl_xor(sum, m);
    const float inv = 1.f / sum;

#pragma unroll
    for (int t = 0; t < 4; ++t) {               // write ALL 128 slots (0 pad)
        int k = lane + t * 32;
        w[h][k] = (k < d) ? ev[t] * inv : 0.f;
    }
    __syncthreads();

    // --- aggregation: 8-wide, branch-free, 2 accumulators ---
    float acc0 = 0.f, acc1 = 0.f;
    for (int k = 0; k < d8; k += 8) {
        int4   ja = *(const int4*)  &cs[k];
        int4   jb = *(const int4*)  &cs[k + 4];
        float4 wa = *(const float4*)&w[h][k];
        float4 wb = *(const float4*)&w[h][k + 4];
        float g0 = Wh_t[(size_t)ja.x * 256 + tid];
        float g1 = Wh_t[(size_t)ja.y * 256 + tid];
        float g2 = Wh_t[(size_t)ja.z * 256 + tid];
        float g3 = Wh_t[(size_t)ja.w * 256 + tid];
        float g4 = Wh_t[(size_t)jb.x * 256 + tid];
        float g5 = Wh_t[(size_t)jb.y * 256 + tid];
        float g6 = Wh_t[(size_t)jb.z * 256 + tid];
        float g7 = Wh_t[(size_t)jb.w * 256 + tid];
        acc0 += wa.x * g0 + wa.y * g1 + wa.z * g2 + wa.w * g3;
        acc1 += wb.x * g4 + wb.y * g5 + wb.z * g6 + wb.w * g7;
    }
    float acc = acc0 + acc1;
    acc = acc > 0.f ? acc : __expf(acc) - 1.f;   // elu (concat heads)
    hs[tid] = acc;
    __syncthreads();

    // --- Who[r,:] = hrow @ W_out, split over 4 waves ---
    const int fo = tid & 63, q = tid >> 6;
    float p = 0.f;
#pragma unroll
    for (int c = q * 64; c < q * 64 + 64; ++c) p += hs[c] * Wout[c * NOUT + fo];
    part[q][fo] = p;
    __syncthreads();

    if (tid < 64) {
        float who = part[0][tid] + part[1][tid] + part[2][tid] + part[3][tid];
        Who[(size_t)r * NOUT + tid] = who;
        float v1 = who * aout[tid];
        float v2 = who * aout[NOUT + tid];
#pragma unroll
        for (int m = 32; m >= 1; m >>= 1) {
            v1 += __shfl_xor(v1, m);
            v2 += __shfl_xor(v2, m);
        }
        if (tid == 0) { o1[r] = v1; o2[r] = v2; }
    }
}

// ---------------------------------------------------------------------------
// K3 (attn2): one block (256 thr) per row. Block softmax; wave-split-k gather
// in 8-wide groups; LDS combine; tanh; fp32 store.
// ---------------------------------------------------------------------------
__global__ __launch_bounds__(256) void k_attn2(
    const int* __restrict__ col, const int* __restrict__ deg,
    const float* __restrict__ Who, const float* __restrict__ o1,
    const float* __restrict__ o2, float* __restrict__ out)
{
    const int r   = blockIdx.x;
    const int tid = threadIdx.x;
    const int wv  = tid >> 6, lane = tid & 63;

    __shared__ int   cs[MAXDEG];
    __shared__ float w[MAXDEG];
    __shared__ float part[4][NOUT];
    __shared__ float redm[4], reds[4];

    const int d = deg[r];
    for (int k = tid; k < MAXDEG; k += 256)
        cs[k] = (k < d) ? col[r * MAXDEG + k] : 0;
    __syncthreads();

    // --- scores (tid<128 holds one neighbor each) + block softmax ---
    const float sr = o1[r];
    float e = -3.4e38f;
    if (tid < d) {
        e = sr + o2[cs[tid]];
        e = e > 0.f ? e : ALPHA * e;
    }
    float mx = e;
#pragma unroll
    for (int m = 32; m >= 1; m >>= 1) mx = fmaxf(mx, __shfl_xor(mx, m));
    if (lane == 0) redm[wv] = mx;
    __syncthreads();
    mx = fmaxf(fmaxf(redm[0], redm[1]), fmaxf(redm[2], redm[3]));

    float p = (tid < d) ? __expf(e - mx) : 0.f;
    float s = p;
#pragma unroll
    for (int m = 32; m >= 1; m >>= 1) s += __shfl_xor(s, m);
    if (lane == 0) reds[wv] = s;
    __syncthreads();
    const float inv = 1.f / (reds[0] + reds[1] + reds[2] + reds[3]);
    if (tid < MAXDEG) w[tid] = p * inv;          // zeros beyond d
    __syncthreads();

    // --- gather split-k: wave wv takes 8-wide groups {wv*8, wv*8+32, ...} ---
    const int kup = (d + 31) & ~31;              // padded: w=0, cs=0 beyond d
    float acc0 = 0.f, acc1 = 0.f;
    for (int k = wv * 8; k < kup; k += 32) {
        int4   ja = *(const int4*)  &cs[k];
        int4   jb = *(const int4*)  &cs[k + 4];
        float4 wa = *(const float4*)&w[k];
        float4 wb = *(const float4*)&w[k + 4];
        acc0 += wa.x * Who[(size_t)ja.x * NOUT + lane];
        acc0 += wa.y * Who[(size_t)ja.y * NOUT + lane];
        acc0 += wa.z * Who[(size_t)ja.z * NOUT + lane];
        acc0 += wa.w * Who[(size_t)ja.w * NOUT + lane];
        acc1 += wb.x * Who[(size_t)jb.x * NOUT + lane];
        acc1 += wb.y * Who[(size_t)jb.y * NOUT + lane];
        acc1 += wb.z * Who[(size_t)jb.z * NOUT + lane];
        acc1 += wb.w * Who[(size_t)jb.w * NOUT + lane];
    }
    part[wv][lane] = acc0 + acc1;
    __syncthreads();

    if (tid < NOUT)
        out[(size_t)r * NOUT + tid] =
            tanhf(part[0][tid] + part[1][tid] + part[2][tid] + part[3][tid]);
}

// ---------------------------------------------------------------------------
extern "C" void kernel_launch(void* const* d_in, const int* in_sizes, int n_in,
                              void* d_out, int out_size, void* d_ws, size_t ws_size,
                              hipStream_t stream) {
    const float* x    = (const float*)d_in[0];   // [4096,64]
    const float* adj  = (const float*)d_in[1];   // [4096,4096]
    const float* ie   = (const float*)d_in[2];   // [4096,32]
    const float* Wsp  = (const float*)d_in[3];   // [6,64,32]
    const float* asp  = (const float*)d_in[4];   // [6,64]
    const float* Wint = (const float*)d_in[5];   // [2,64,32]
    const float* aint = (const float*)d_in[6];   // [2,64]
    const float* Wout = (const float*)d_in[7];   // [256,64]
    const float* aout = (const float*)d_in[8];   // [128]
    float* out = (float*)d_out;                  // [4096,64]

    float* ws    = (float*)d_ws;
    float* Wh_t  = ws;                    // [4096][256]  node-major
    float* src   = Wh_t + 1048576;        // [8][4096]
    float* dst_t = src  + 32768;          // [4096][8]
    float* Who   = dst_t + 32768;         // [4096][64]
    float* o1    = Who  + 262144;         // [4096]
    float* o2    = o1   + 4096;           // [4096]
    int*   col   = (int*)(o2 + 4096);     // [4096][128]
    int*   deg   = col + 4096 * MAXDEG;   // [4096]

    k_fused1  <<<N / NPB, 256, 0, stream>>>(x, ie, (const float4*)adj, Wsp, asp,
                                            Wint, aint, Wh_t, src, dst_t, col, deg);
    k_attn1who<<<N,       256, 0, stream>>>(col, deg, Wh_t, src, dst_t, Wout, aout,
                                            Who, o1, o2);
    k_attn2   <<<N,       256, 0, stream>>>(col, deg, Who, o1, o2, out);
}